// Round 1
// baseline (490.351 us; speedup 1.0000x reference)
//
#include <hip/hip_runtime.h>

#define CN   62
#define FIN  512
#define FOUT 256
#define KCH  5
#define JF   (CN*FIN)     // 31744
#define JF4  (JF/4)       // 7936
#define CC   (CN*CN)      // 3844

typedef float v4 __attribute__((ext_vector_type(4)));

// ---------------------------------------------------------------------------
// Kernel 1 (single block): adjacency MLP -> threshold -> Laplacian -> P_0..P_4
// ---------------------------------------------------------------------------
__global__ __launch_bounds__(1024) void k_setup(
    const float* __restrict__ coord, const float* __restrict__ w1,
    const float* __restrict__ b1, const float* __restrict__ w2,
    const float* __restrict__ b2, float* __restrict__ Pg)
{
    __shared__ float sL[CC];     // A, then L (in-place per-element)
    __shared__ float sB0[CC];
    __shared__ float sB1[CC];
    __shared__ float sB2[CC];
    __shared__ float sDis[CN];
    const int tid = threadIdx.x;

    // W_star = relu(coord @ w1 + b1) @ w2 + b2 ; threshold & zero diagonal
    for (int e = tid; e < CC; e += 1024) {
        int i = e / CN, j = e % CN;
        float c0 = coord[e*4+0], c1 = coord[e*4+1];
        float c2 = coord[e*4+2], c3 = coord[e*4+3];
        float acc = b2[0];
        for (int u = 0; u < 64; ++u) {
            float h = b1[u] + c0*w1[u] + c1*w1[64+u] + c2*w1[128+u] + c3*w1[192+u];
            acc += fmaxf(h, 0.0f) * w2[u];
        }
        sL[e] = (acc > 0.1f && i != j) ? acc : 0.0f;
    }
    __syncthreads();

    if (tid < CN) {
        float d = 0.f;
        for (int j = 0; j < CN; ++j) d += sL[tid*CN + j];
        sDis[tid] = (d > 0.f) ? (1.0f / sqrtf(d)) : 0.f;
    }
    __syncthreads();

    // L = -(D^-1/2 A D^-1/2); P0 = I; P1 = L
    for (int e = tid; e < CC; e += 1024) {
        int i = e / CN, j = e % CN;
        float l = -(sDis[i] * sL[e] * sDis[j]);
        sL[e]  = l;
        float id = (i == j) ? 1.f : 0.f;
        sB0[e] = id;
        sB1[e] = l;
        Pg[e]      = id;
        Pg[CC + e] = l;
    }
    __syncthreads();

    // P_k = 2 L P_{k-1} - P_{k-2}
    float* bufs[3] = { sB0, sB1, sB2 };
    for (int k = 2; k < KCH; ++k) {
        float* Pa = bufs[(k-2) % 3];
        float* Pb = bufs[(k-1) % 3];
        float* Pc = bufs[k % 3];
        for (int e = tid; e < CC; e += 1024) {
            int i = e / CN, j = e % CN;
            float s = 0.f;
            for (int m = 0; m < CN; ++m) s += sL[i*CN + m] * Pb[m*CN + j];
            float v = 2.f * s - Pa[e];
            Pc[e] = v;
            Pg[k*CC + e] = v;
        }
        __syncthreads();
    }
}

// ---------------------------------------------------------------------------
// Kernel 2: R[k][n][j][fo] = sum_c P_k[c,j] * fc_w[(c*256+fo)*2+n]
// 158720 threads, 62 MAC each
// ---------------------------------------------------------------------------
__global__ __launch_bounds__(256) void k_R(
    const float* __restrict__ Pg, const float* __restrict__ fcw,
    float* __restrict__ R)
{
    int t  = blockIdx.x * 256 + threadIdx.x;   // t == ((k*2+n)*CN + j)*256 + fo
    int fo = t & 255;
    int j  = (t >> 8) % CN;
    int n  = (t / (256*CN)) & 1;
    int k  = t / (256*CN*2);
    float acc = 0.f;
    for (int c = 0; c < CN; ++c)
        acc += Pg[k*CC + c*CN + j] * fcw[(c*FOUT + fo)*2 + n];
    R[t] = acc;
}

// ---------------------------------------------------------------------------
// Kernel 3: G[n][j*512+f] = conv_w * sum_k sum_fo chebW[k][f][fo] * R[k][n][j][fo]
// 63488 threads, 1280 MAC each (float4)
// ---------------------------------------------------------------------------
__global__ __launch_bounds__(256) void k_G(
    const float* __restrict__ chebW, const float* __restrict__ R,
    const float* __restrict__ convw, float* __restrict__ G)
{
    int t  = blockIdx.x * 256 + threadIdx.x;   // n*JF + jf
    int n  = t / JF;
    int jf = t % JF;
    int j  = jf >> 9;
    int f  = jf & 511;
    float acc = 0.f;
    for (int k = 0; k < KCH; ++k) {
        const v4* cwp = (const v4*)(chebW + (size_t)(k*FIN + f) * FOUT);
        const v4* rp  = (const v4*)(R + (size_t)((k*2 + n)*CN + j) * FOUT);
        #pragma unroll 4
        for (int q = 0; q < FOUT/4; ++q) {
            v4 a = cwp[q], b = rp[q];
            acc += a.x*b.x + a.y*b.y + a.z*b.z + a.w*b.w;
        }
    }
    G[t] = convw[0] * acc;
}

// ---------------------------------------------------------------------------
// Kernel 4: const[n] = sum_{c,fo} (cw*cheb_b[fo] + cb) * fc_w[..,n] + fc_b[n]
// ---------------------------------------------------------------------------
__global__ __launch_bounds__(128) void k_const(
    const float* __restrict__ fcw, const float* __restrict__ chb,
    const float* __restrict__ cw, const float* __restrict__ cb,
    const float* __restrict__ fcb, float* __restrict__ constv)
{
    int n = threadIdx.x >> 6, lane = threadIdx.x & 63;
    float w = cw[0], b = cb[0];
    float acc = 0.f;
    for (int idx = lane; idx < CN*FOUT; idx += 64) {
        int fo = idx & 255;
        acc += (w * chb[fo] + b) * fcw[idx*2 + n];
    }
    for (int o = 32; o > 0; o >>= 1) acc += __shfl_down(acc, o, 64);
    if (lane == 0) constv[n] = acc + fcb[n];
}

// ---------------------------------------------------------------------------
// Kernel 5 (main, HBM-bound): out[b,n] = sum_jf x[b,jf]*G[n][jf] + const[n]
// 4 batch rows per block; nontemporal x loads; 256 threads
// ---------------------------------------------------------------------------
__global__ __launch_bounds__(256) void k_main(
    const float* __restrict__ x, const float* __restrict__ G,
    const float* __restrict__ constv, float* __restrict__ out)
{
    const int tid = threadIdx.x;
    const int b0  = blockIdx.x * 4;
    const v4* g0 = (const v4*)(G);
    const v4* g1 = (const v4*)(G + JF);
    const v4* x0 = (const v4*)(x + (size_t)b0 * JF);

    float a00=0, a01=0, a10=0, a11=0, a20=0, a21=0, a30=0, a31=0;

    #pragma unroll 2
    for (int i = tid; i < JF4; i += 256) {
        v4 gg0 = g0[i];
        v4 gg1 = g1[i];
        v4 x0v = __builtin_nontemporal_load(&x0[i]);
        v4 x1v = __builtin_nontemporal_load(&x0[JF4 + i]);
        v4 x2v = __builtin_nontemporal_load(&x0[2*JF4 + i]);
        v4 x3v = __builtin_nontemporal_load(&x0[3*JF4 + i]);
        a00 += x0v.x*gg0.x + x0v.y*gg0.y + x0v.z*gg0.z + x0v.w*gg0.w;
        a01 += x0v.x*gg1.x + x0v.y*gg1.y + x0v.z*gg1.z + x0v.w*gg1.w;
        a10 += x1v.x*gg0.x + x1v.y*gg0.y + x1v.z*gg0.z + x1v.w*gg0.w;
        a11 += x1v.x*gg1.x + x1v.y*gg1.y + x1v.z*gg1.z + x1v.w*gg1.w;
        a20 += x2v.x*gg0.x + x2v.y*gg0.y + x2v.z*gg0.z + x2v.w*gg0.w;
        a21 += x2v.x*gg1.x + x2v.y*gg1.y + x2v.z*gg1.z + x2v.w*gg1.w;
        a30 += x3v.x*gg0.x + x3v.y*gg0.y + x3v.z*gg0.z + x3v.w*gg0.w;
        a31 += x3v.x*gg1.x + x3v.y*gg1.y + x3v.z*gg1.z + x3v.w*gg1.w;
    }

    float vals[8] = { a00, a01, a10, a11, a20, a21, a30, a31 };
    for (int o = 32; o > 0; o >>= 1) {
        #pragma unroll
        for (int q = 0; q < 8; ++q) vals[q] += __shfl_down(vals[q], o, 64);
    }

    __shared__ float sred[4][8];
    int wave = tid >> 6, lane = tid & 63;
    if (lane == 0) {
        #pragma unroll
        for (int q = 0; q < 8; ++q) sred[wave][q] = vals[q];
    }
    __syncthreads();
    if (tid < 8) {
        float s = sred[0][tid] + sred[1][tid] + sred[2][tid] + sred[3][tid];
        int r = tid >> 1, n = tid & 1;
        out[(b0 + r)*2 + n] = s + constv[n];
    }
}

// ---------------------------------------------------------------------------
extern "C" void kernel_launch(void* const* d_in, const int* in_sizes, int n_in,
                              void* d_out, int out_size, void* d_ws, size_t ws_size,
                              hipStream_t stream)
{
    const float* x     = (const float*)d_in[0];
    const float* coord = (const float*)d_in[1];
    const float* aw1   = (const float*)d_in[2];
    const float* ab1   = (const float*)d_in[3];
    const float* aw2   = (const float*)d_in[4];
    const float* ab2   = (const float*)d_in[5];
    const float* chebW = (const float*)d_in[6];
    const float* chebb = (const float*)d_in[7];
    const float* convw = (const float*)d_in[8];
    const float* convb = (const float*)d_in[9];
    const float* fcw   = (const float*)d_in[10];
    const float* fcb   = (const float*)d_in[11];
    float* out = (float*)d_out;

    float* ws = (float*)d_ws;
    float* Pg = ws;                         // 5*3844   = 19220
    float* R  = Pg + KCH*CC;                // 5*2*62*256 = 158720
    float* G  = R + KCH*2*CN*FOUT;          // 2*31744  = 63488
    float* cv = G + 2*JF;                   // 2

    k_setup<<<1, 1024, 0, stream>>>(coord, aw1, ab1, aw2, ab2, Pg);
    k_R    <<<(KCH*2*CN*FOUT)/256, 256, 0, stream>>>(Pg, fcw, R);
    k_G    <<<(2*JF)/256, 256, 0, stream>>>(chebW, R, convw, G);
    k_const<<<1, 128, 0, stream>>>(fcw, chebb, convw, convb, fcb, cv);
    k_main <<<2048/4, 256, 0, stream>>>(x, G, cv, out);
}

// Round 2
// 422.307 us; speedup vs baseline: 1.1611x; 1.1611x over previous
//
#include <hip/hip_runtime.h>

#define CN   62
#define FIN  512
#define FOUT 256
#define KCH  5
#define JF   (CN*FIN)     // 31744
#define JF4  (JF/4)       // 7936
#define CC   (CN*CN)      // 3844

typedef float v4 __attribute__((ext_vector_type(4)));
typedef float v2 __attribute__((ext_vector_type(2)));

// ---------------------------------------------------------------------------
// Kernel 1 (merged): block 0 -> adjacency MLP + Laplacian + Chebyshev P_0..P_4
//                    blocks 1..160 -> S[k][c][n][f] = sum_fo chebW[k][f][fo]*fcw[c,fo,n]
// The two jobs have NO data dependency, so they share one launch.
// ---------------------------------------------------------------------------
__global__ __launch_bounds__(512) void k_pre(
    const float* __restrict__ coord, const float* __restrict__ w1,
    const float* __restrict__ b1, const float* __restrict__ w2,
    const float* __restrict__ b2, const float* __restrict__ chebW,
    const float* __restrict__ fcw, float* __restrict__ Pg,
    float* __restrict__ S2)
{
    __shared__ float smem[24128];    // 96.5 KB, aliased per role
    const int tid = threadIdx.x;
    const int bid = blockIdx.x;

    if (bid == 0) {
        // ---- setup: MLP adjacency -> threshold -> Laplacian -> P_k ----
        float* sL  = smem;            // 3844
        float* sB0 = smem + 3844;
        float* sB1 = smem + 7688;
        float* sB2 = smem + 11532;
        float* sDis= smem + 15376;    // 62

        for (int e = tid; e < CC; e += 512) {
            int i = e / CN, j = e % CN;
            float c0 = coord[e*4+0], c1 = coord[e*4+1];
            float c2 = coord[e*4+2], c3 = coord[e*4+3];
            float acc = b2[0];
            for (int u = 0; u < 64; ++u) {
                float h = b1[u] + c0*w1[u] + c1*w1[64+u] + c2*w1[128+u] + c3*w1[192+u];
                acc += fmaxf(h, 0.0f) * w2[u];
            }
            sL[e] = (acc > 0.1f && i != j) ? acc : 0.0f;
        }
        __syncthreads();

        if (tid < CN) {
            float d = 0.f;
            for (int j = 0; j < CN; ++j) d += sL[tid*CN + j];
            sDis[tid] = (d > 0.f) ? (1.0f / sqrtf(d)) : 0.f;
        }
        __syncthreads();

        for (int e = tid; e < CC; e += 512) {
            int i = e / CN, j = e % CN;
            float l = -(sDis[i] * sL[e] * sDis[j]);
            sL[e]  = l;
            float id = (i == j) ? 1.f : 0.f;
            sB0[e] = id;
            sB1[e] = l;
            Pg[e]      = id;
            Pg[CC + e] = l;
        }
        __syncthreads();

        float* bufs[3] = { sB0, sB1, sB2 };
        for (int k = 2; k < KCH; ++k) {
            float* Pa = bufs[(k-2) % 3];
            float* Pb = bufs[(k-1) % 3];
            float* Pc = bufs[k % 3];
            for (int e = tid; e < CC; e += 512) {
                int i = e / CN, j = e % CN;
                float s = 0.f;
                for (int m = 0; m < CN; ++m) s += sL[i*CN + m] * Pb[m*CN + j];
                float v = 2.f * s - Pa[e];
                Pc[e] = v;
                Pg[k*CC + e] = v;
            }
            __syncthreads();
        }
    } else {
        // ---- S: S2[((k*62+c)*2+n)*512+f] = sum_fo chebW[k][f][fo]*fcw[c*512+2*fo+n]
        // grid decode: 160 blocks = 5 k * 16 f-tiles(32) * 2 c-halves(31)
        int b  = bid - 1;
        int k  = b >> 5;
        int r  = b & 31;
        int f0 = (r >> 1) * 32;
        int ch = r & 1;

        float* sW = smem;           // [32][258] padded: 8256 floats
        float* sF = smem + 8256;    // [31][512]: 15872 floats

        // stage chebW f-tile (coalesced)
        const float* cwb = chebW + (size_t)(k*FIN + f0) * FOUT;
        for (int i = tid; i < 32*256; i += 512) {
            int rr = i >> 8, q = i & 255;
            sW[rr*258 + q] = cwb[rr*256 + q];
        }
        // stage fcw c-half (coalesced; rows are contiguous 512 floats)
        const float* fb = fcw + (size_t)(ch*31) * 512;
        for (int i = tid; i < 31*512; i += 512) {
            sF[i] = fb[i];
        }
        __syncthreads();

        int f_local = tid & 31;
        int c_local = tid >> 5;          // 0..15
        const float* wrow = sW + f_local*258;

        #pragma unroll
        for (int pass = 0; pass < 2; ++pass) {
            int c_l = c_local + pass*16;
            if (c_l >= 31) break;
            const v2* frow = (const v2*)(sF + c_l*512);
            float a0 = 0.f, a1 = 0.f;
            #pragma unroll 4
            for (int fo = 0; fo < 256; ++fo) {
                float w = wrow[fo];
                v2 fv = frow[fo];
                a0 += w * fv.x;
                a1 += w * fv.y;
            }
            size_t base = ((size_t)((k*62 + ch*31 + c_l)*2))*512 + f0 + f_local;
            S2[base]       = a0;   // n=0
            S2[base + 512] = a1;   // n=1
        }
    }
}

// ---------------------------------------------------------------------------
// Kernel 2: blocks 0..123 -> G[n][j*512+f] = cw * sum_{k,c} P_k[c,j]*S2[k,c,n,f]
//           block 124     -> const[n] (independent of everything above)
// ---------------------------------------------------------------------------
__global__ __launch_bounds__(256) void k_G3(
    const float* __restrict__ Pg, const float* __restrict__ S2,
    const float* __restrict__ chebb, const float* __restrict__ convw,
    const float* __restrict__ convb, const float* __restrict__ fcw,
    const float* __restrict__ fcb, float* __restrict__ G,
    float* __restrict__ constv)
{
    const int tid = threadIdx.x;
    const int bid = blockIdx.x;
    __shared__ float sP[310];
    __shared__ float sp4[4];

    if (bid < 124) {
        int n = bid / CN, j = bid % CN;
        for (int i = tid; i < 310; i += 256) {
            int k = i / CN, c = i % CN;
            sP[i] = Pg[k*CC + c*CN + j];
        }
        __syncthreads();

        const v2* s2 = (const v2*)S2;
        float a0 = 0.f, a1 = 0.f;
        #pragma unroll 5
        for (int i = 0; i < 310; ++i) {
            float p = sP[i];
            v2 v = s2[(size_t)(i*2 + n)*256 + tid];
            a0 += p * v.x;
            a1 += p * v.y;
        }
        float cw = convw[0];
        v2 res; res.x = cw*a0; res.y = cw*a1;
        ((v2*)(G + (size_t)n*JF + j*512))[tid] = res;
    } else {
        // const[n] = sum_{c,fo} (cw*chebb[fo] + cb)*fcw[(c*256+fo)*2+n] + fcb[n]
        int w = tid >> 6, lane = tid & 63;
        int n = w & 1, half = w >> 1;
        float cw = convw[0], cb = convb[0];
        float acc = 0.f;
        for (int idx = lane + 64*half; idx < CN*FOUT; idx += 128) {
            int fo = idx & 255;
            acc += (cw * chebb[fo] + cb) * fcw[idx*2 + n];
        }
        for (int o = 32; o > 0; o >>= 1) acc += __shfl_down(acc, o, 64);
        if (lane == 0) sp4[w] = acc;
        __syncthreads();
        if (tid < 2) constv[tid] = sp4[tid] + sp4[tid + 2] + fcb[tid];
    }
}

// ---------------------------------------------------------------------------
// Kernel 3 (main, HBM-bound): out[b,n] = sum_jf x[b,jf]*G[n][jf] + const[n]
// ---------------------------------------------------------------------------
__global__ __launch_bounds__(256) void k_main(
    const float* __restrict__ x, const float* __restrict__ G,
    const float* __restrict__ constv, float* __restrict__ out)
{
    const int tid = threadIdx.x;
    const int b0  = blockIdx.x * 4;
    const v4* g0 = (const v4*)(G);
    const v4* g1 = (const v4*)(G + JF);
    const v4* x0 = (const v4*)(x + (size_t)b0 * JF);

    float a00=0, a01=0, a10=0, a11=0, a20=0, a21=0, a30=0, a31=0;

    #pragma unroll 2
    for (int i = tid; i < JF4; i += 256) {
        v4 gg0 = g0[i];
        v4 gg1 = g1[i];
        v4 x0v = __builtin_nontemporal_load(&x0[i]);
        v4 x1v = __builtin_nontemporal_load(&x0[JF4 + i]);
        v4 x2v = __builtin_nontemporal_load(&x0[2*JF4 + i]);
        v4 x3v = __builtin_nontemporal_load(&x0[3*JF4 + i]);
        a00 += x0v.x*gg0.x + x0v.y*gg0.y + x0v.z*gg0.z + x0v.w*gg0.w;
        a01 += x0v.x*gg1.x + x0v.y*gg1.y + x0v.z*gg1.z + x0v.w*gg1.w;
        a10 += x1v.x*gg0.x + x1v.y*gg0.y + x1v.z*gg0.z + x1v.w*gg0.w;
        a11 += x1v.x*gg1.x + x1v.y*gg1.y + x1v.z*gg1.z + x1v.w*gg1.w;
        a20 += x2v.x*gg0.x + x2v.y*gg0.y + x2v.z*gg0.z + x2v.w*gg0.w;
        a21 += x2v.x*gg1.x + x2v.y*gg1.y + x2v.z*gg1.z + x2v.w*gg1.w;
        a30 += x3v.x*gg0.x + x3v.y*gg0.y + x3v.z*gg0.z + x3v.w*gg0.w;
        a31 += x3v.x*gg1.x + x3v.y*gg1.y + x3v.z*gg1.z + x3v.w*gg1.w;
    }

    float vals[8] = { a00, a01, a10, a11, a20, a21, a30, a31 };
    for (int o = 32; o > 0; o >>= 1) {
        #pragma unroll
        for (int q = 0; q < 8; ++q) vals[q] += __shfl_down(vals[q], o, 64);
    }

    __shared__ float sred[4][8];
    int wave = tid >> 6, lane = tid & 63;
    if (lane == 0) {
        #pragma unroll
        for (int q = 0; q < 8; ++q) sred[wave][q] = vals[q];
    }
    __syncthreads();
    if (tid < 8) {
        float s = sred[0][tid] + sred[1][tid] + sred[2][tid] + sred[3][tid];
        int r = tid >> 1, n = tid & 1;
        out[(b0 + r)*2 + n] = s + constv[n];
    }
}

// ---------------------------------------------------------------------------
extern "C" void kernel_launch(void* const* d_in, const int* in_sizes, int n_in,
                              void* d_out, int out_size, void* d_ws, size_t ws_size,
                              hipStream_t stream)
{
    const float* x     = (const float*)d_in[0];
    const float* coord = (const float*)d_in[1];
    const float* aw1   = (const float*)d_in[2];
    const float* ab1   = (const float*)d_in[3];
    const float* aw2   = (const float*)d_in[4];
    const float* ab2   = (const float*)d_in[5];
    const float* chebW = (const float*)d_in[6];
    const float* chebb = (const float*)d_in[7];
    const float* convw = (const float*)d_in[8];
    const float* convb = (const float*)d_in[9];
    const float* fcw   = (const float*)d_in[10];
    const float* fcb   = (const float*)d_in[11];
    float* out = (float*)d_out;

    float* ws = (float*)d_ws;
    float* Pg = ws;                         // 5*3844           = 19220
    float* S2 = Pg + KCH*CC;                // 5*62*2*512       = 317440
    float* G  = S2 + KCH*CN*2*FIN;          // 2*31744          = 63488
    float* cv = G + 2*JF;                   // 2

    k_pre <<<161, 512, 0, stream>>>(coord, aw1, ab1, aw2, ab2, chebW, fcw, Pg, S2);
    k_G3  <<<125, 256, 0, stream>>>(Pg, S2, chebb, convw, convb, fcw, fcb, G, cv);
    k_main<<<512, 256, 0, stream>>>(x, G, cv, out);
}